// Round 5
// baseline (78.387 us; speedup 1.0000x reference)
//
#include <hip/hip_runtime.h>
#include <math.h>

#define N_POINTS   262144
#define NUM_FREQS  10
#define NUM_VOXELS 512
#define NWIN       256          // windows of 1024 points
#define SEGCAP     768          // per-voxel segment capacity (max count ~587)

// W is (1536,63) row-major fp32; voxel v uses rows 3v..3v+2 (189 floats).
// Packed: Wp[v] = 3 rows x 64 bf16 (col63 zero) = 384 B, 16B-aligned.
//
// R5 pipeline (no global atomics anywhere):
//   A: pack W  +  per-window LDS histogram -> counts[win][v]
//   B: per-voxel exclusive scan over windows -> prefix[win][v], totals[v]
//   C: scatter (x,y,z,row) float4 to slot v*SEGCAP + prefix + LDS-rank
//   D: compute; v = blk/3 is block-uniform -> W gather is a broadcast.

__device__ __forceinline__ unsigned short f2bf(float f) {
    unsigned int u = __float_as_uint(f);
    return (unsigned short)((u + 0x7fffu + ((u >> 16) & 1u)) >> 16);   // RNE
}
__device__ __forceinline__ float bf_lo(unsigned int u) { return __uint_as_float(u << 16); }
__device__ __forceinline__ float bf_hi(unsigned int u) { return __uint_as_float(u & 0xffff0000u); }

// posenc (double-angle recurrence; 2^f*x exact in fp32, err ~1e-4) + dot
// against the 3 packed bf16 rows of voxel v (24 uint4 loads).
__device__ __forceinline__ void posenc_pack_dot(
    float x0, float x1, float x2, const unsigned short* __restrict__ Wp, int v,
    float& a0, float& a1, float& a2)
{
    float enc[64];
    enc[0] = x0; enc[1] = x1; enc[2] = x2;
    enc[63] = 0.0f;

    float s0, c0, s1, c1, s2, c2;
    sincosf(x0, &s0, &c0);
    sincosf(x1, &s1, &c1);
    sincosf(x2, &s2, &c2);
    #pragma unroll
    for (int f = 0; f < NUM_FREQS; ++f) {
        const int b = 3 + 6*f;           // [s0 s1 s2 c0 c1 c2]
        enc[b+0] = s0; enc[b+1] = s1; enc[b+2] = s2;
        enc[b+3] = c0; enc[b+4] = c1; enc[b+5] = c2;
        if (f < NUM_FREQS - 1) {
            const float ns0 = 2.0f*s0*c0, nc0 = c0*c0 - s0*s0;
            const float ns1 = 2.0f*s1*c1, nc1 = c1*c1 - s1*s1;
            const float ns2 = 2.0f*s2*c2, nc2 = c2*c2 - s2*s2;
            s0 = ns0; c0 = nc0; s1 = ns1; c1 = nc1; s2 = ns2; c2 = nc2;
        }
    }

    const uint4* __restrict__ wb = (const uint4*)(Wp + (size_t)v * 192);
    float acc[3];
    #pragma unroll
    for (int r = 0; r < 3; ++r) {
        float a = 0.0f;
        #pragma unroll
        for (int k = 0; k < 8; ++k) {
            const uint4 q = wb[r * 8 + k];
            const int e = 8 * k;
            a += bf_lo(q.x) * enc[e+0] + bf_hi(q.x) * enc[e+1]
               + bf_lo(q.y) * enc[e+2] + bf_hi(q.y) * enc[e+3]
               + bf_lo(q.z) * enc[e+4] + bf_hi(q.z) * enc[e+5]
               + bf_lo(q.w) * enc[e+6] + bf_hi(q.w) * enc[e+7];
        }
        acc[r] = a;
    }
    a0 = acc[0]; a1 = acc[1]; a2 = acc[2];
}

// ---------------------------------------------------------------------------
// A: blocks [0,96): pack W fp32->bf16.  blocks [96,352): window histogram.
// ---------------------------------------------------------------------------
__global__ __launch_bounds__(1024) void kA_pack_hist(
    const float* __restrict__ W, const int* __restrict__ voxel_ids,
    unsigned short* __restrict__ Wp, int* __restrict__ counts)
{
    const int t = threadIdx.x;
    if (blockIdx.x < 96) {
        const int gid = blockIdx.x * 1024 + t;       // [0, 98304) = 512*192
        const int v = gid / 192, e = gid % 192;
        const int row = e >> 6, col = e & 63;
        Wp[v * 192 + e] = (col < 63) ? f2bf(W[v * 189 + row * 63 + col])
                                     : (unsigned short)0;
    } else {
        __shared__ int hist[NUM_VOXELS];
        const int w = blockIdx.x - 96;
        if (t < NUM_VOXELS) hist[t] = 0;
        __syncthreads();
        atomicAdd(&hist[voxel_ids[w * 1024 + t]], 1);
        __syncthreads();
        if (t < NUM_VOXELS) counts[w * NUM_VOXELS + t] = hist[t];
    }
}

// ---------------------------------------------------------------------------
// B: one block per voxel; exclusive scan of counts over the 256 windows.
// ---------------------------------------------------------------------------
__global__ __launch_bounds__(NWIN) void kB_scan(
    const int* __restrict__ counts, int* __restrict__ prefix,
    int* __restrict__ totals)
{
    __shared__ int tmp[NWIN];
    const int v = blockIdx.x, t = threadIdx.x;
    const int c = counts[t * NUM_VOXELS + v];
    tmp[t] = c;
    __syncthreads();
    #pragma unroll
    for (int off = 1; off < NWIN; off <<= 1) {
        int add = (t >= off) ? tmp[t - off] : 0;
        __syncthreads();
        tmp[t] += add;
        __syncthreads();
    }
    prefix[t * NUM_VOXELS + v] = tmp[t] - c;         // exclusive
    if (t == NWIN - 1) totals[v] = tmp[t];
}

// ---------------------------------------------------------------------------
// C: scatter payload into voxel segments. LDS atomics only.
// ---------------------------------------------------------------------------
__global__ __launch_bounds__(1024) void kC_scatter(
    const float* __restrict__ X, const int* __restrict__ row_ids,
    const int* __restrict__ voxel_ids, const int* __restrict__ prefix,
    float4* __restrict__ buf)
{
    __shared__ int cur[NUM_VOXELS];
    const int t = threadIdx.x, w = blockIdx.x;
    if (t < NUM_VOXELS) cur[t] = t * SEGCAP + prefix[w * NUM_VOXELS + t];
    __syncthreads();

    const int i = w * 1024 + t;
    const int v = voxel_ids[i];
    float4 val;
    val.x = X[3*i]; val.y = X[3*i+1]; val.z = X[3*i+2];
    val.w = __int_as_float(row_ids[i]);
    const int pos = atomicAdd(&cur[v], 1);           // rank (order irrelevant)
    if (pos < (v + 1) * SEGCAP) buf[pos] = val;      // safety clamp
}

// ---------------------------------------------------------------------------
// D: compute. grid = 512*SEGCAP/256 = 1536 blocks; v = blk/3 block-uniform,
// so the W gather is a same-address broadcast (~1 line per instruction).
// ---------------------------------------------------------------------------
__global__ __launch_bounds__(256) void kD_compute(
    const float4* __restrict__ buf, const unsigned short* __restrict__ Wp,
    const int* __restrict__ totals, float* __restrict__ out)
{
    const int v = blockIdx.x / 3;
    const int j = (blockIdx.x % 3) * 256 + threadIdx.x;   // slot within segment
    if (j >= totals[v]) return;

    const float4 q = buf[v * SEGCAP + j];
    float a0, a1, a2;
    posenc_pack_dot(q.x, q.y, q.z, Wp, v, a0, a1, a2);

    const int r = __float_as_int(q.w);
    out[3*r + 0] = a0;
    out[3*r + 1] = a1;
    out[3*r + 2] = a2;
}

// ---------------------------------------------------------------------------
// Fallback (R1 kernel) if ws too small.
// ---------------------------------------------------------------------------
__global__ __launch_bounds__(256) void voxlin_fallback(
    const float* __restrict__ X, const float* __restrict__ W,
    const int* __restrict__ row_ids, const int* __restrict__ voxel_ids,
    float* __restrict__ out)
{
    const int i = blockIdx.x * 256 + threadIdx.x;
    if (i >= N_POINTS) return;
    const float x0 = X[3*i], x1 = X[3*i+1], x2 = X[3*i+2];
    const int v = voxel_ids[i];
    const float* __restrict__ w0 = W + v * 189;
    const float* __restrict__ w1 = w0 + 63;
    const float* __restrict__ w2 = w0 + 126;
    float a0 = x0*w0[0] + x1*w0[1] + x2*w0[2];
    float a1 = x0*w1[0] + x1*w1[1] + x2*w1[2];
    float a2 = x0*w2[0] + x1*w2[1] + x2*w2[2];
    float s0, c0, s1, c1, s2, c2;
    sincosf(x0, &s0, &c0); sincosf(x1, &s1, &c1); sincosf(x2, &s2, &c2);
    #pragma unroll
    for (int f = 0; f < NUM_FREQS; ++f) {
        const int b = 3 + 6*f;
        a0 += s0*w0[b] + s1*w0[b+1] + s2*w0[b+2] + c0*w0[b+3] + c1*w0[b+4] + c2*w0[b+5];
        a1 += s0*w1[b] + s1*w1[b+1] + s2*w1[b+2] + c0*w1[b+3] + c1*w1[b+4] + c2*w1[b+5];
        a2 += s0*w2[b] + s1*w2[b+1] + s2*w2[b+2] + c0*w2[b+3] + c1*w2[b+4] + c2*w2[b+5];
        if (f < NUM_FREQS - 1) {
            const float ns0 = 2.0f*s0*c0, nc0 = c0*c0 - s0*s0;
            const float ns1 = 2.0f*s1*c1, nc1 = c1*c1 - s1*s1;
            const float ns2 = 2.0f*s2*c2, nc2 = c2*c2 - s2*s2;
            s0 = ns0; c0 = nc0; s1 = ns1; c1 = nc1; s2 = ns2; c2 = nc2;
        }
    }
    const int rr = row_ids[i];
    out[3*rr] = a0; out[3*rr+1] = a1; out[3*rr+2] = a2;
}

// ---------------------------------------------------------------------------
extern "C" void kernel_launch(void* const* d_in, const int* in_sizes, int n_in,
                              void* d_out, int out_size, void* d_ws, size_t ws_size,
                              hipStream_t stream) {
    const float* X         = (const float*)d_in[0];
    const float* W         = (const float*)d_in[1];
    const int*   row_ids   = (const int*)d_in[2];
    const int*   voxel_ids = (const int*)d_in[3];
    float*       out       = (float*)d_out;

    // ws layout
    const size_t wpBytes     = (size_t)NUM_VOXELS * 192 * 2;        // 196608
    const size_t countsBytes = (size_t)NWIN * NUM_VOXELS * 4;       // 524288
    const size_t prefixBytes = countsBytes;                         // 524288
    const size_t totalsBytes = (size_t)NUM_VOXELS * 4;              // 2048
    const size_t headBytes   = wpBytes + countsBytes + prefixBytes + totalsBytes;
    const size_t bufBytes    = (size_t)NUM_VOXELS * SEGCAP * 16;    // 6291456
    const size_t need        = headBytes + bufBytes + 16;

    if (ws_size >= need) {
        char* ws = (char*)d_ws;
        unsigned short* Wp     = (unsigned short*)ws;
        int*            counts = (int*)(ws + wpBytes);
        int*            prefix = (int*)(ws + wpBytes + countsBytes);
        int*            totals = (int*)(ws + wpBytes + countsBytes + prefixBytes);
        // align buf to 16B
        size_t bufOff = (headBytes + 15) & ~(size_t)15;
        float4*         buf    = (float4*)(ws + bufOff);

        kA_pack_hist<<<96 + NWIN, 1024, 0, stream>>>(W, voxel_ids, Wp, counts);
        kB_scan<<<NUM_VOXELS, NWIN, 0, stream>>>(counts, prefix, totals);
        kC_scatter<<<NWIN, 1024, 0, stream>>>(X, row_ids, voxel_ids, prefix, buf);
        kD_compute<<<NUM_VOXELS * (SEGCAP / 256), 256, 0, stream>>>(buf, Wp, totals, out);
    } else {
        voxlin_fallback<<<(N_POINTS + 255) / 256, 256, 0, stream>>>(X, W, row_ids, voxel_ids, out);
    }
}

// Round 6
// 74.085 us; speedup vs baseline: 1.0581x; 1.0581x over previous
//
#include <hip/hip_runtime.h>
#include <math.h>

#define N_POINTS   262144
#define NUM_FREQS  10
#define NUM_VOXELS 512

// W is (1536,63) row-major fp32; voxel v uses rows 3v..3v+2 (189 floats).
// Packed into ws as bf16: Wp[v] = 3 rows x 64 bf16 (col63 zero) = 384 B,
// 64B-aligned -> each point's gather is 24 uint4 loads over exactly 6 lines.
//
// R6: single fused kernel. Block-local counting sort by voxel (1024-pt
// window) so a wave's lanes share voxel cache-lines on the W gather, THEN
// invert the permutation inside LDS so the out-writes stay in original
// coalesced order (R4 paid ~64 lines/wave on scattered out stores; R5's
// global bucketing paid the same wall on the other side).

__device__ __forceinline__ unsigned short f2bf(float f) {
    unsigned int u = __float_as_uint(f);
    return (unsigned short)((u + 0x7fffu + ((u >> 16) & 1u)) >> 16);   // RNE
}
__device__ __forceinline__ float bf_lo(unsigned int u) { return __uint_as_float(u << 16); }
__device__ __forceinline__ float bf_hi(unsigned int u) { return __uint_as_float(u & 0xffff0000u); }

// posenc (double-angle recurrence; 2^f*x exact in fp32, recurrence err ~1e-4)
// + dot against the 3 packed bf16 rows of voxel v (24 uint4 loads, 6 lines).
__device__ __forceinline__ void posenc_pack_dot(
    float x0, float x1, float x2, const unsigned short* __restrict__ Wp, int v,
    float& a0, float& a1, float& a2)
{
    float enc[64];
    enc[0] = x0; enc[1] = x1; enc[2] = x2;
    enc[63] = 0.0f;

    float s0, c0, s1, c1, s2, c2;
    sincosf(x0, &s0, &c0);
    sincosf(x1, &s1, &c1);
    sincosf(x2, &s2, &c2);
    #pragma unroll
    for (int f = 0; f < NUM_FREQS; ++f) {
        const int b = 3 + 6*f;           // [s0 s1 s2 c0 c1 c2]
        enc[b+0] = s0; enc[b+1] = s1; enc[b+2] = s2;
        enc[b+3] = c0; enc[b+4] = c1; enc[b+5] = c2;
        if (f < NUM_FREQS - 1) {
            const float ns0 = 2.0f*s0*c0, nc0 = c0*c0 - s0*s0;
            const float ns1 = 2.0f*s1*c1, nc1 = c1*c1 - s1*s1;
            const float ns2 = 2.0f*s2*c2, nc2 = c2*c2 - s2*s2;
            s0 = ns0; c0 = nc0; s1 = ns1; c1 = nc1; s2 = ns2; c2 = nc2;
        }
    }

    const uint4* __restrict__ wb = (const uint4*)(Wp + (size_t)v * 192);
    float acc[3];
    #pragma unroll
    for (int r = 0; r < 3; ++r) {
        float a = 0.0f;
        #pragma unroll
        for (int k = 0; k < 8; ++k) {
            const uint4 q = wb[r * 8 + k];
            const int e = 8 * k;
            a += bf_lo(q.x) * enc[e+0] + bf_hi(q.x) * enc[e+1]
               + bf_lo(q.y) * enc[e+2] + bf_hi(q.y) * enc[e+3]
               + bf_lo(q.z) * enc[e+4] + bf_hi(q.z) * enc[e+5]
               + bf_lo(q.w) * enc[e+6] + bf_hi(q.w) * enc[e+7];
        }
        acc[r] = a;
    }
    a0 = acc[0]; a1 = acc[1]; a2 = acc[2];
}

// ---------------------------------------------------------------------------
// Pass 1: pack W (fp32 1536x63) -> Wp (bf16 512 x 3 x 64). Runs every call
// (ws is re-poisoned before every timed launch).  96 blocks x 1024.
// ---------------------------------------------------------------------------
__global__ __launch_bounds__(1024) void pack_w(
    const float* __restrict__ W, unsigned short* __restrict__ Wp)
{
    const int gid = blockIdx.x * 1024 + threadIdx.x;   // [0, 98304) = 512*192
    const int v = gid / 192, e = gid % 192;
    const int row = e >> 6, col = e & 63;
    Wp[v * 192 + e] = (col < 63) ? f2bf(W[v * 189 + row * 63 + col])
                                 : (unsigned short)0;
}

// ---------------------------------------------------------------------------
// Pass 2: fused sort + compute + unpermute.  Grid = 256 x 1024 = N.
//  1. LDS hist + scan over 512 bins -> counting-sort slots
//  2. scatter (x,y,z,v) into pts[] by slot; remember own slot (mypos)
//  3. compute point at slot t (neighbors share voxels -> shared gather lines)
//  4. write result back to pts[t] (same slot read -> no race), barrier
//  5. thread t reads pts[mypos] = ITS point's result; out-write coalesced
// ---------------------------------------------------------------------------
__global__ __launch_bounds__(1024, 1) void voxlin_fused(
    const float* __restrict__ X,
    const unsigned short* __restrict__ Wp,
    const int* __restrict__ row_ids,
    const int* __restrict__ voxel_ids,
    float* __restrict__ out)
{
    __shared__ float4 pts[1024];         // 16 KB: (x,y,z,v) then (a0,a1,a2,-)
    __shared__ int    hist[NUM_VOXELS];
    __shared__ int    cur[NUM_VOXELS];

    const int t = threadIdx.x;
    const int i = blockIdx.x * 1024 + t;

    const int   v  = voxel_ids[i];
    const float x0 = X[3*i + 0];
    const float x1 = X[3*i + 1];
    const float x2 = X[3*i + 2];
    const int   r  = row_ids[i];         // stays in this thread's registers

    if (t < NUM_VOXELS) hist[t] = 0;
    __syncthreads();
    atomicAdd(&hist[v], 1);
    __syncthreads();

    // inclusive Hillis-Steele scan over 512 bins (all threads hit barriers)
    const int c = (t < NUM_VOXELS) ? hist[t] : 0;
    #pragma unroll
    for (int off = 1; off < NUM_VOXELS; off <<= 1) {
        int add = (t < NUM_VOXELS && t >= off) ? hist[t - off] : 0;
        __syncthreads();
        if (t < NUM_VOXELS) hist[t] += add;
        __syncthreads();
    }
    if (t < NUM_VOXELS) cur[t] = hist[t] - c;    // exclusive start = cursor
    __syncthreads();

    const int mypos = atomicAdd(&cur[v], 1);     // own point's sorted slot
    pts[mypos] = make_float4(x0, x1, x2, __int_as_float(v));
    __syncthreads();

    // compute for the point sitting at slot t
    const float4 q  = pts[t];
    const int    sv = __float_as_int(q.w);
    float a0, a1, a2;
    posenc_pack_dot(q.x, q.y, q.z, Wp, sv, a0, a1, a2);

    pts[t] = make_float4(a0, a1, a2, 0.0f);      // same slot we read: no race
    __syncthreads();

    // unpermute: fetch own point's result, write in original (coalesced) order
    const float4 res = pts[mypos];
    out[3*r + 0] = res.x;
    out[3*r + 1] = res.y;
    out[3*r + 2] = res.z;
}

// ---------------------------------------------------------------------------
// Fallback (R1 kernel) if ws too small for the 192 KB packed table.
// ---------------------------------------------------------------------------
__global__ __launch_bounds__(256) void voxlin_fallback(
    const float* __restrict__ X, const float* __restrict__ W,
    const int* __restrict__ row_ids, const int* __restrict__ voxel_ids,
    float* __restrict__ out)
{
    const int i = blockIdx.x * 256 + threadIdx.x;
    if (i >= N_POINTS) return;
    const float x0 = X[3*i], x1 = X[3*i+1], x2 = X[3*i+2];
    const int v = voxel_ids[i];
    const float* __restrict__ w0 = W + v * 189;
    const float* __restrict__ w1 = w0 + 63;
    const float* __restrict__ w2 = w0 + 126;
    float a0 = x0*w0[0] + x1*w0[1] + x2*w0[2];
    float a1 = x0*w1[0] + x1*w1[1] + x2*w1[2];
    float a2 = x0*w2[0] + x1*w2[1] + x2*w2[2];
    float s0, c0, s1, c1, s2, c2;
    sincosf(x0, &s0, &c0); sincosf(x1, &s1, &c1); sincosf(x2, &s2, &c2);
    #pragma unroll
    for (int f = 0; f < NUM_FREQS; ++f) {
        const int b = 3 + 6*f;
        a0 += s0*w0[b] + s1*w0[b+1] + s2*w0[b+2] + c0*w0[b+3] + c1*w0[b+4] + c2*w0[b+5];
        a1 += s0*w1[b] + s1*w1[b+1] + s2*w1[b+2] + c0*w1[b+3] + c1*w1[b+4] + c2*w1[b+5];
        a2 += s0*w2[b] + s1*w2[b+1] + s2*w2[b+2] + c0*w2[b+3] + c1*w2[b+4] + c2*w2[b+5];
        if (f < NUM_FREQS - 1) {
            const float ns0 = 2.0f*s0*c0, nc0 = c0*c0 - s0*s0;
            const float ns1 = 2.0f*s1*c1, nc1 = c1*c1 - s1*s1;
            const float ns2 = 2.0f*s2*c2, nc2 = c2*c2 - s2*s2;
            s0 = ns0; c0 = nc0; s1 = ns1; c1 = nc1; s2 = ns2; c2 = nc2;
        }
    }
    const int rr = row_ids[i];
    out[3*rr] = a0; out[3*rr+1] = a1; out[3*rr+2] = a2;
}

// ---------------------------------------------------------------------------
extern "C" void kernel_launch(void* const* d_in, const int* in_sizes, int n_in,
                              void* d_out, int out_size, void* d_ws, size_t ws_size,
                              hipStream_t stream) {
    const float* X         = (const float*)d_in[0];
    const float* W         = (const float*)d_in[1];
    const int*   row_ids   = (const int*)d_in[2];
    const int*   voxel_ids = (const int*)d_in[3];
    float*       out       = (float*)d_out;

    const size_t need = (size_t)NUM_VOXELS * 192 * sizeof(unsigned short); // 192 KB

    if (ws_size >= need) {
        unsigned short* Wp = (unsigned short*)d_ws;
        pack_w<<<96, 1024, 0, stream>>>(W, Wp);
        voxlin_fused<<<N_POINTS / 1024, 1024, 0, stream>>>(X, Wp, row_ids, voxel_ids, out);
    } else {
        voxlin_fallback<<<(N_POINTS + 255) / 256, 256, 0, stream>>>(X, W, row_ids, voxel_ids, out);
    }
}